// Round 5
// baseline (814.001 us; speedup 1.0000x reference)
//
#include <hip/hip_runtime.h>
#include <math.h>

#define NROWS 8192
#define DIM   1024
#define DIM2  2048           // merged hi|lo K dimension
#define KSEL  5
#define TOPK  6
#define QB    128            // query rows per block
#define KBT   128            // key cols per tile
#define NSLICE 16
#define KPS   (NROWS / NSLICE)   // keys per slice = 512
#define NKT   (KPS / KBT)        // key tiles per slice = 4
#define SST   68                 // Sims row stride (floats), 16B aligned

typedef __attribute__((ext_vector_type(8))) short bf16x8;
typedef __attribute__((ext_vector_type(4))) float f32x4;

// ---------------------------------------------------------------------------
// ws layout:
//   [0]          : int match counter
//   [256]        : Q2 bf16[8192][2048]  (hi | lo)   32 MB
//   [+32M]       : K2 bf16[8192][2048]  (hi | lo)   32 MB
//   [+64M]       : partials float2[8192][32][TOPK]  (~12.6 MB)
// sims = Q2·K2^T = qh·kh + qh·kl + ql·kh + ql·kl; lolo term ~2^-18 relative,
// below fp32 accumulation noise — ONE K=2048 bf16 GEMM suffices.
// LDS = 8+8+17.4 KB = 33.4 KB -> 4 blocks/CU; grid 1024 = exactly 4/CU.
// ---------------------------------------------------------------------------

__device__ __forceinline__ unsigned short f2bf(float x) {
    unsigned u = __float_as_uint(x);
    unsigned r = (u + 0x7fffu + ((u >> 16) & 1u)) >> 16;   // RNE
    return (unsigned short)r;
}
__device__ __forceinline__ float bf2f(unsigned short h) {
    return __uint_as_float(((unsigned)h) << 16);
}

// full tie-break compare (merge kernel only — arbitrary id order there)
__device__ __forceinline__ bool better(float v, int id, float v2, int id2) {
    return (v > v2) || (v == v2 && id < id2);
}
__device__ __forceinline__ void insert6(float v, int id, float* tv, int* ti) {
    if (!better(v, id, tv[TOPK - 1], ti[TOPK - 1])) return;
    int j = TOPK - 1;
    while (j > 0 && better(v, id, tv[j - 1], ti[j - 1])) {
        tv[j] = tv[j - 1]; ti[j] = ti[j - 1]; --j;
    }
    tv[j] = v; ti[j] = id;
}

// strict insert: candidate ids strictly ascending per thread stream, so
// strict '>' implements the lower-index tie-break exactly.
__device__ __forceinline__ void ins(float v, int id, float* tv, int* ti) {
    if (v <= tv[TOPK - 1]) return;
    int j = TOPK - 1;
    while (j > 0 && v > tv[j - 1]) {
        tv[j] = tv[j - 1]; ti[j] = ti[j - 1]; --j;
    }
    tv[j] = v; ti[j] = id;
}

__device__ __forceinline__ void async16(const unsigned short* g, unsigned short* l) {
    __builtin_amdgcn_global_load_lds(
        (const __attribute__((address_space(1))) void*)g,
        (__attribute__((address_space(3))) void*)l, 16, 0, 0);
}

// --- 1) normalize + split into hi/lo bf16, packed [hi | lo] per row ---------
__global__ __launch_bounds__(256) void prep_kernel(
        const float* __restrict__ q, const float* __restrict__ kb,
        unsigned short* __restrict__ Q2, unsigned short* __restrict__ K2) {
    const int b = blockIdx.x;
    const bool isQ = (b < NROWS);
    const int r = isQ ? b : b - NROWS;
    const float* src = (isQ ? q : kb) + (size_t)r * DIM;
    unsigned short* D = (isQ ? Q2 : K2) + (size_t)r * DIM2;

    float4 v = *(const float4*)(src + threadIdx.x * 4);
    float s = v.x * v.x + v.y * v.y + v.z * v.z + v.w * v.w;
    for (int o = 32; o; o >>= 1) s += __shfl_down(s, o, 64);
    __shared__ float wsum[4];
    __shared__ float inv_s;
    int lane = threadIdx.x & 63, wid = threadIdx.x >> 6;
    if (lane == 0) wsum[wid] = s;
    __syncthreads();
    if (threadIdx.x == 0)
        inv_s = 1.0f / fmaxf(sqrtf(wsum[0] + wsum[1] + wsum[2] + wsum[3]), 1e-12f);
    __syncthreads();
    const float inv = inv_s;

    float xs[4] = {v.x * inv, v.y * inv, v.z * inv, v.w * inv};
    unsigned short h[4], lo[4];
#pragma unroll
    for (int i = 0; i < 4; ++i) {
        h[i]  = f2bf(xs[i]);
        lo[i] = f2bf(xs[i] - bf2f(h[i]));
    }
    *(ushort4*)(D + threadIdx.x * 4)       = make_ushort4(h[0], h[1], h[2], h[3]);
    *(ushort4*)(D + DIM + threadIdx.x * 4) = make_ushort4(lo[0], lo[1], lo[2], lo[3]);
}

// --- 2) single K=2048 MFMA GEMM + fused per-row top-6 -----------------------
__global__ __launch_bounds__(256) void gemm_topk_kernel(
        const unsigned short* __restrict__ Q2, const unsigned short* __restrict__ K2,
        float2* __restrict__ partials) {
    __shared__ unsigned short As[QB * 32];    // 8 KB
    __shared__ unsigned short Bs[KBT * 32];   // 8 KB
    __shared__ float Sims[64 * SST];          // 17.4 KB (64x64 scan window)

    const int tid = threadIdx.x;
    const int w = tid >> 6, l = tid & 63;
    const int l15 = l & 15, l4 = l >> 4;
    const int qbase = blockIdx.x * QB;
    const int sbase = blockIdx.y * KPS;
    const int wrh = w & 1;               // this wave's row-half
    const int wch = w >> 1;              // this wave's col-half

    const int srow  = tid >> 2;          // staging row 0..63 (second half +64)
    const int skoff = (tid & 3) * 8;     // k offset in bf16 elems (16 B chunks)

    float tv[TOPK]; int ti[TOPK];
#pragma unroll
    for (int i = 0; i < TOPK; ++i) { tv[i] = -INFINITY; ti[i] = 0x7fffffff; }
    const int trow = tid >> 1;           // persistent top-k row 0..127
    const int tq   = tid & 1;            // 32-col quarter selector
    const int myrh = trow >> 6;          // which row-half this thread owns

    const int fa_off = (wrh * 64 + l15) * 32 + l4 * 8;   // + mt*512
    const int fb_off = (wch * 64 + l15) * 32 + l4 * 8;   // + nt*512

    const size_t abase = (size_t)(qbase + srow) * DIM2 + skoff;

    for (int kt = 0; kt < NKT; ++kt) {
        f32x4 acc[4][4];
#pragma unroll
        for (int mt = 0; mt < 4; ++mt)
#pragma unroll
            for (int nt = 0; nt < 4; ++nt) acc[mt][nt] = (f32x4){0.f, 0.f, 0.f, 0.f};

        const size_t bbase = (size_t)(sbase + kt * KBT + srow) * DIM2 + skoff;

#pragma unroll 1
        for (int k0 = 0; k0 < DIM2; k0 += 32) {
            async16(Q2 + abase + k0,                       As + tid * 8);
            async16(Q2 + abase + (size_t)64 * DIM2 + k0,   As + 2048 + tid * 8);
            async16(K2 + bbase + k0,                       Bs + tid * 8);
            async16(K2 + bbase + (size_t)64 * DIM2 + k0,   Bs + 2048 + tid * 8);
            __syncthreads();   // drains vmcnt (global_load_lds)
            bf16x8 af[4], bf[4];
#pragma unroll
            for (int mt = 0; mt < 4; ++mt)
                af[mt] = *(const bf16x8*)(As + fa_off + mt * 512);
#pragma unroll
            for (int nt = 0; nt < 4; ++nt)
                bf[nt] = *(const bf16x8*)(Bs + fb_off + nt * 512);
#pragma unroll
            for (int mt = 0; mt < 4; ++mt)
#pragma unroll
                for (int nt = 0; nt < 4; ++nt)
                    acc[mt][nt] = __builtin_amdgcn_mfma_f32_16x16x32_bf16(
                        af[mt], bf[nt], acc[mt][nt], 0, 0, 0);
            __syncthreads();
        }

        // ---- fused top-k: four 64x64 phases through a 64-row Sims ----------
        const int tile0 = sbase + kt * KBT;
#pragma unroll
        for (int rh = 0; rh < 2; ++rh) {
#pragma unroll
            for (int ch = 0; ch < 2; ++ch) {
                if (wrh == rh && wch == ch) {   // owning wave writes 64x64
#pragma unroll
                    for (int mt = 0; mt < 4; ++mt) {
                        const int r0 = mt * 16 + l4 * 4;
#pragma unroll
                        for (int nt = 0; nt < 4; ++nt) {
                            const int c = nt * 16 + l15;
                            Sims[(r0 + 0) * SST + c] = acc[mt][nt].x;
                            Sims[(r0 + 1) * SST + c] = acc[mt][nt].y;
                            Sims[(r0 + 2) * SST + c] = acc[mt][nt].z;
                            Sims[(r0 + 3) * SST + c] = acc[mt][nt].w;
                        }
                    }
                }
                __syncthreads();
                if (myrh == rh) {               // 128 owning threads scan
                    const float* sp = Sims + (trow & 63) * SST + tq * 32;
                    const int idc0 = tile0 + ch * 64 + tq * 32;
#pragma unroll
                    for (int j = 0; j < 8; ++j) {
                        float4 v = *(const float4*)(sp + 4 * j);
                        float m = fmaxf(fmaxf(v.x, v.y), fmaxf(v.z, v.w));
                        if (m > tv[TOPK - 1]) {
                            const int idc = idc0 + 4 * j;
                            ins(v.x, idc + 0, tv, ti);
                            ins(v.y, idc + 1, tv, ti);
                            ins(v.z, idc + 2, tv, ti);
                            ins(v.w, idc + 3, tv, ti);
                        }
                    }
                }
                __syncthreads();
            }
        }
    }

    size_t off = (((size_t)(qbase + trow) * 2 * NSLICE) + blockIdx.y * 2 + tq) * TOPK;
#pragma unroll
    for (int i = 0; i < TOPK; ++i)
        partials[off + i] = make_float2(tv[i], __int_as_float(ti[i]));
}

// --- 3) merge 32 partial lists per row, count matches on ranks 1..5 ---------
__global__ __launch_bounds__(256) void merge_kernel(
        const float2* __restrict__ partials,
        const int* __restrict__ query_ids, const int* __restrict__ key_ids,
        int* __restrict__ counter) {
    int row = blockIdx.x * blockDim.x + threadIdx.x;
    float tv[TOPK]; int ti[TOPK];
#pragma unroll
    for (int i = 0; i < TOPK; ++i) { tv[i] = -INFINITY; ti[i] = 0x7fffffff; }
    const float2* p = partials + (size_t)row * 2 * NSLICE * TOPK;
    for (int l = 0; l < 2 * NSLICE * TOPK; ++l) {
        float2 e = p[l];
        insert6(e.x, __float_as_int(e.y), tv, ti);
    }
    int qid = query_ids[row];
    int cnt = 0;
#pragma unroll
    for (int r = 1; r < TOPK; ++r)
        cnt += (key_ids[ti[r]] == qid) ? 1 : 0;

    for (int o = 32; o; o >>= 1) cnt += __shfl_down(cnt, o, 64);
    __shared__ int sc[4];
    int lane = threadIdx.x & 63, wid = threadIdx.x >> 6;
    if (lane == 0) sc[wid] = cnt;
    __syncthreads();
    if (threadIdx.x == 0) atomicAdd(counter, sc[0] + sc[1] + sc[2] + sc[3]);
}

// --- 4) finalize ------------------------------------------------------------
__global__ void finalize_kernel(const int* __restrict__ counter,
                                float* __restrict__ out) {
    out[0] = (float)(*counter) / (float)(NROWS * KSEL);
}

extern "C" void kernel_launch(void* const* d_in, const int* in_sizes, int n_in,
                              void* d_out, int out_size, void* d_ws, size_t ws_size,
                              hipStream_t stream) {
    (void)in_sizes; (void)n_in; (void)out_size; (void)ws_size;
    const int*   query_ids = (const int*)d_in[0];
    const int*   key_ids   = (const int*)d_in[1];
    const float* q         = (const float*)d_in[2];
    const float* kb        = (const float*)d_in[3];

    char* ws = (char*)d_ws;
    const size_t MB32 = (size_t)NROWS * DIM2 * sizeof(unsigned short);  // 32 MB
    int*            counter  = (int*)ws;
    unsigned short* Q2       = (unsigned short*)(ws + 256);
    unsigned short* K2       = (unsigned short*)(ws + 256 + MB32);
    float2*         partials = (float2*)(ws + 256 + 2 * MB32);

    hipMemsetAsync(counter, 0, sizeof(int), stream);
    prep_kernel<<<2 * NROWS, 256, 0, stream>>>(q, kb, Q2, K2);
    gemm_topk_kernel<<<dim3(NROWS / QB, NSLICE), 256, 0, stream>>>(Q2, K2, partials);
    merge_kernel<<<NROWS / 256, 256, 0, stream>>>(partials, query_ids, key_ids, counter);
    finalize_kernel<<<1, 1, 0, stream>>>(counter, (float*)d_out);
}

// Round 6
// 638.018 us; speedup vs baseline: 1.2758x; 1.2758x over previous
//
#include <hip/hip_runtime.h>
#include <math.h>

#define NROWS 8192
#define DIM   1024
#define DIM2  2048           // merged hi|lo K dimension
#define KSEL  5
#define TOPK  6
#define QB    128            // query rows per block
#define KBT   128            // key cols per tile
#define NSLICE 8
#define KPS   (NROWS / NSLICE)   // keys per slice = 1024
#define NKT   (KPS / KBT)        // key tiles per slice = 8
#define SST   68                 // Sims row stride (floats), 16B aligned

typedef __attribute__((ext_vector_type(8))) short bf16x8;
typedef __attribute__((ext_vector_type(4))) float f32x4;

// ---------------------------------------------------------------------------
// ws layout:
//   [0]          : int match counter
//   [256]        : Q2 bf16[8192][2048]  (hi | lo)   32 MB
//   [+32M]       : K2 bf16[8192][2048]  (hi | lo)   32 MB
//   [+64M]       : partials float2[8192][16][TOPK]  (~6.3 MB)
// sims = Q2·K2^T; lolo term ~2^-18 relative — ONE K=2048 bf16 GEMM.
// Packing: regs (76 VGPR + 64 AGPR = 140) cap at 3 blocks/CU; grid 512
// = exactly 2/CU -> no straggler tail (round-5 lesson: LDS shrink is
// useless, register file binds; round-4 lesson: grid>residency = 1.27x tail).
// ---------------------------------------------------------------------------

__device__ __forceinline__ unsigned short f2bf(float x) {
    unsigned u = __float_as_uint(x);
    unsigned r = (u + 0x7fffu + ((u >> 16) & 1u)) >> 16;   // RNE
    return (unsigned short)r;
}
__device__ __forceinline__ float bf2f(unsigned short h) {
    return __uint_as_float(((unsigned)h) << 16);
}

// full tie-break compare (merge kernel only — arbitrary id order there)
__device__ __forceinline__ bool better(float v, int id, float v2, int id2) {
    return (v > v2) || (v == v2 && id < id2);
}
__device__ __forceinline__ void insert6(float v, int id, float* tv, int* ti) {
    if (!better(v, id, tv[TOPK - 1], ti[TOPK - 1])) return;
    int j = TOPK - 1;
    while (j > 0 && better(v, id, tv[j - 1], ti[j - 1])) {
        tv[j] = tv[j - 1]; ti[j] = ti[j - 1]; --j;
    }
    tv[j] = v; ti[j] = id;
}

// strict insert: candidate ids strictly ascending per thread stream, so
// strict '>' implements the lower-index tie-break exactly.
__device__ __forceinline__ void ins(float v, int id, float* tv, int* ti) {
    if (v <= tv[TOPK - 1]) return;
    int j = TOPK - 1;
    while (j > 0 && v > tv[j - 1]) {
        tv[j] = tv[j - 1]; ti[j] = ti[j - 1]; --j;
    }
    tv[j] = v; ti[j] = id;
}

__device__ __forceinline__ void async16(const unsigned short* g, unsigned short* l) {
    __builtin_amdgcn_global_load_lds(
        (const __attribute__((address_space(1))) void*)g,
        (__attribute__((address_space(3))) void*)l, 16, 0, 0);
}

// --- 1) normalize + split into hi/lo bf16, packed [hi | lo] per row ---------
__global__ __launch_bounds__(256) void prep_kernel(
        const float* __restrict__ q, const float* __restrict__ kb,
        unsigned short* __restrict__ Q2, unsigned short* __restrict__ K2) {
    const int b = blockIdx.x;
    const bool isQ = (b < NROWS);
    const int r = isQ ? b : b - NROWS;
    const float* src = (isQ ? q : kb) + (size_t)r * DIM;
    unsigned short* D = (isQ ? Q2 : K2) + (size_t)r * DIM2;

    float4 v = *(const float4*)(src + threadIdx.x * 4);
    float s = v.x * v.x + v.y * v.y + v.z * v.z + v.w * v.w;
    for (int o = 32; o; o >>= 1) s += __shfl_down(s, o, 64);
    __shared__ float wsum[4];
    __shared__ float inv_s;
    int lane = threadIdx.x & 63, wid = threadIdx.x >> 6;
    if (lane == 0) wsum[wid] = s;
    __syncthreads();
    if (threadIdx.x == 0)
        inv_s = 1.0f / fmaxf(sqrtf(wsum[0] + wsum[1] + wsum[2] + wsum[3]), 1e-12f);
    __syncthreads();
    const float inv = inv_s;

    float xs[4] = {v.x * inv, v.y * inv, v.z * inv, v.w * inv};
    unsigned short h[4], lo[4];
#pragma unroll
    for (int i = 0; i < 4; ++i) {
        h[i]  = f2bf(xs[i]);
        lo[i] = f2bf(xs[i] - bf2f(h[i]));
    }
    *(ushort4*)(D + threadIdx.x * 4)       = make_ushort4(h[0], h[1], h[2], h[3]);
    *(ushort4*)(D + DIM + threadIdx.x * 4) = make_ushort4(lo[0], lo[1], lo[2], lo[3]);
}

// --- 2) single K=2048 MFMA GEMM + fused per-row top-6 -----------------------
__global__ __launch_bounds__(256) void gemm_topk_kernel(
        const unsigned short* __restrict__ Q2, const unsigned short* __restrict__ K2,
        float2* __restrict__ partials) {
    __shared__ unsigned short As[QB * 32];    // 8 KB
    __shared__ unsigned short Bs[KBT * 32];   // 8 KB
    __shared__ float Sims[128 * SST];         // 34 KB

    const int tid = threadIdx.x;
    const int w = tid >> 6, l = tid & 63;
    const int l15 = l & 15, l4 = l >> 4;
    const int qbase = blockIdx.x * QB;
    const int sbase = blockIdx.y * KPS;
    const int mbase = (w & 1) * 64, nbase = (w >> 1) * 64;

    const int srow  = tid >> 2;          // staging row 0..63 (second half +64)
    const int skoff = (tid & 3) * 8;     // k offset in bf16 elems (16 B chunks)

    float tv[TOPK]; int ti[TOPK];
#pragma unroll
    for (int i = 0; i < TOPK; ++i) { tv[i] = -INFINITY; ti[i] = 0x7fffffff; }
    const int trow = tid >> 1;           // persistent top-k row 0..127
    const int tq   = tid & 1;            // 32-col quarter selector

    const int fa_off = (mbase + l15) * 32 + l4 * 8;   // + mt*512
    const int fb_off = (nbase + l15) * 32 + l4 * 8;   // + nt*512

    const size_t abase = (size_t)(qbase + srow) * DIM2 + skoff;

    for (int kt = 0; kt < NKT; ++kt) {
        f32x4 acc[4][4];
#pragma unroll
        for (int mt = 0; mt < 4; ++mt)
#pragma unroll
            for (int nt = 0; nt < 4; ++nt) acc[mt][nt] = (f32x4){0.f, 0.f, 0.f, 0.f};

        const size_t bbase = (size_t)(sbase + kt * KBT + srow) * DIM2 + skoff;

#pragma unroll 1
        for (int k0 = 0; k0 < DIM2; k0 += 32) {
            async16(Q2 + abase + k0,                       As + tid * 8);
            async16(Q2 + abase + (size_t)64 * DIM2 + k0,   As + 2048 + tid * 8);
            async16(K2 + bbase + k0,                       Bs + tid * 8);
            async16(K2 + bbase + (size_t)64 * DIM2 + k0,   Bs + 2048 + tid * 8);
            __syncthreads();   // drains vmcnt (global_load_lds)
            bf16x8 af[4], bf[4];
#pragma unroll
            for (int mt = 0; mt < 4; ++mt)
                af[mt] = *(const bf16x8*)(As + fa_off + mt * 512);
#pragma unroll
            for (int nt = 0; nt < 4; ++nt)
                bf[nt] = *(const bf16x8*)(Bs + fb_off + nt * 512);
#pragma unroll
            for (int mt = 0; mt < 4; ++mt)
#pragma unroll
                for (int nt = 0; nt < 4; ++nt)
                    acc[mt][nt] = __builtin_amdgcn_mfma_f32_16x16x32_bf16(
                        af[mt], bf[nt], acc[mt][nt], 0, 0, 0);
            __syncthreads();
        }

        // ---- fused top-k: two col-half phases, all 256 threads scan --------
        const int tile0 = sbase + kt * KBT;

        // phase A: waves 0,1 (nbase==0) hold cols 0..63 for all 128 rows
        if (nbase == 0) {
#pragma unroll
            for (int mt = 0; mt < 4; ++mt) {
                const int r0 = mbase + mt * 16 + l4 * 4;
#pragma unroll
                for (int nt = 0; nt < 4; ++nt) {
                    const int c = nt * 16 + l15;        // local col 0..63
                    Sims[(r0 + 0) * SST + c] = acc[mt][nt].x;
                    Sims[(r0 + 1) * SST + c] = acc[mt][nt].y;
                    Sims[(r0 + 2) * SST + c] = acc[mt][nt].z;
                    Sims[(r0 + 3) * SST + c] = acc[mt][nt].w;
                }
            }
        }
        __syncthreads();
        {
            const float* sp = Sims + trow * SST + tq * 32;
            const int idc0 = tile0 + tq * 32;
#pragma unroll
            for (int j = 0; j < 8; ++j) {
                float4 v = *(const float4*)(sp + 4 * j);
                float m = fmaxf(fmaxf(v.x, v.y), fmaxf(v.z, v.w));
                if (m > tv[TOPK - 1]) {
                    const int idc = idc0 + 4 * j;
                    ins(v.x, idc + 0, tv, ti);
                    ins(v.y, idc + 1, tv, ti);
                    ins(v.z, idc + 2, tv, ti);
                    ins(v.w, idc + 3, tv, ti);
                }
            }
        }
        __syncthreads();

        // phase B: waves 2,3 (nbase==64) hold cols 64..127
        if (nbase == 64) {
#pragma unroll
            for (int mt = 0; mt < 4; ++mt) {
                const int r0 = mbase + mt * 16 + l4 * 4;
#pragma unroll
                for (int nt = 0; nt < 4; ++nt) {
                    const int c = nt * 16 + l15;        // local col 0..63
                    Sims[(r0 + 0) * SST + c] = acc[mt][nt].x;
                    Sims[(r0 + 1) * SST + c] = acc[mt][nt].y;
                    Sims[(r0 + 2) * SST + c] = acc[mt][nt].z;
                    Sims[(r0 + 3) * SST + c] = acc[mt][nt].w;
                }
            }
        }
        __syncthreads();
        {
            const float* sp = Sims + trow * SST + tq * 32;
            const int idc0 = tile0 + 64 + tq * 32;
#pragma unroll
            for (int j = 0; j < 8; ++j) {
                float4 v = *(const float4*)(sp + 4 * j);
                float m = fmaxf(fmaxf(v.x, v.y), fmaxf(v.z, v.w));
                if (m > tv[TOPK - 1]) {
                    const int idc = idc0 + 4 * j;
                    ins(v.x, idc + 0, tv, ti);
                    ins(v.y, idc + 1, tv, ti);
                    ins(v.z, idc + 2, tv, ti);
                    ins(v.w, idc + 3, tv, ti);
                }
            }
        }
        // no barrier needed: next kt's staging barrier precedes Sims reuse
    }

    size_t off = (((size_t)(qbase + trow) * 2 * NSLICE) + blockIdx.y * 2 + tq) * TOPK;
#pragma unroll
    for (int i = 0; i < TOPK; ++i)
        partials[off + i] = make_float2(tv[i], __int_as_float(ti[i]));
}

// --- 3) merge 16 partial lists per row, count matches on ranks 1..5 ---------
__global__ __launch_bounds__(256) void merge_kernel(
        const float2* __restrict__ partials,
        const int* __restrict__ query_ids, const int* __restrict__ key_ids,
        int* __restrict__ counter) {
    int row = blockIdx.x * blockDim.x + threadIdx.x;
    float tv[TOPK]; int ti[TOPK];
#pragma unroll
    for (int i = 0; i < TOPK; ++i) { tv[i] = -INFINITY; ti[i] = 0x7fffffff; }
    const float2* p = partials + (size_t)row * 2 * NSLICE * TOPK;
    for (int l = 0; l < 2 * NSLICE * TOPK; ++l) {
        float2 e = p[l];
        insert6(e.x, __float_as_int(e.y), tv, ti);
    }
    int qid = query_ids[row];
    int cnt = 0;
#pragma unroll
    for (int r = 1; r < TOPK; ++r)
        cnt += (key_ids[ti[r]] == qid) ? 1 : 0;

    for (int o = 32; o; o >>= 1) cnt += __shfl_down(cnt, o, 64);
    __shared__ int sc[4];
    int lane = threadIdx.x & 63, wid = threadIdx.x >> 6;
    if (lane == 0) sc[wid] = cnt;
    __syncthreads();
    if (threadIdx.x == 0) atomicAdd(counter, sc[0] + sc[1] + sc[2] + sc[3]);
}

// --- 4) finalize ------------------------------------------------------------
__global__ void finalize_kernel(const int* __restrict__ counter,
                                float* __restrict__ out) {
    out[0] = (float)(*counter) / (float)(NROWS * KSEL);
}

extern "C" void kernel_launch(void* const* d_in, const int* in_sizes, int n_in,
                              void* d_out, int out_size, void* d_ws, size_t ws_size,
                              hipStream_t stream) {
    (void)in_sizes; (void)n_in; (void)out_size; (void)ws_size;
    const int*   query_ids = (const int*)d_in[0];
    const int*   key_ids   = (const int*)d_in[1];
    const float* q         = (const float*)d_in[2];
    const float* kb        = (const float*)d_in[3];

    char* ws = (char*)d_ws;
    const size_t MB32 = (size_t)NROWS * DIM2 * sizeof(unsigned short);  // 32 MB
    int*            counter  = (int*)ws;
    unsigned short* Q2       = (unsigned short*)(ws + 256);
    unsigned short* K2       = (unsigned short*)(ws + 256 + MB32);
    float2*         partials = (float2*)(ws + 256 + 2 * MB32);

    hipMemsetAsync(counter, 0, sizeof(int), stream);
    prep_kernel<<<2 * NROWS, 256, 0, stream>>>(q, kb, Q2, K2);
    gemm_topk_kernel<<<dim3(NROWS / QB, NSLICE), 256, 0, stream>>>(Q2, K2, partials);
    merge_kernel<<<NROWS / 256, 256, 0, stream>>>(partials, query_ids, key_ids, counter);
    finalize_kernel<<<1, 1, 0, stream>>>(counter, (float*)d_out);
}

// Round 7
// 534.682 us; speedup vs baseline: 1.5224x; 1.1933x over previous
//
#include <hip/hip_runtime.h>
#include <math.h>

#define NROWS 8192
#define DIM   1024
#define DIM2  2048           // merged hi|lo K dimension
#define KSEL  5
#define TOPK  6
#define QB    128            // query rows per block
#define KBT   128            // key cols per tile
#define NSLICE 8
#define KPS   (NROWS / NSLICE)   // keys per slice = 1024
#define NKT   (KPS / KBT)        // key tiles per slice = 8
#define SST   68                 // Sims row stride (floats), 16B aligned

typedef __attribute__((ext_vector_type(8))) short bf16x8;
typedef __attribute__((ext_vector_type(4))) float f32x4;

// ---------------------------------------------------------------------------
// ws layout:
//   [0]          : int match counter
//   [256]        : Q2 bf16[8192][2048]  (hi | lo, XOR-swizzled)   32 MB
//   [+32M]       : K2 bf16[8192][2048]  (hi | lo, XOR-swizzled)   32 MB
//   [+64M]       : partials float2[8192][16][TOPK]  (~6.3 MB)
//
// sims = Q2·K2^T; lolo term ~2^-18 relative — ONE K=2048 bf16 GEMM.
//
// XOR swizzle: global_load_lds forces LDS = lane-order (no per-lane scatter),
// so the swizzle lives in GLOBAL: each row's 16B k-chunk kc (within a 64-elem
// k-block) is stored at position kc ^ (row & 7). Fragment reads invert it,
// giving uniform start banks (2 lanes/bank = free) instead of the 2x-conflicted
// pattern of rounds 2-6 (SQ_LDS_BANK_CONFLICT 3.36e7 evidence).
// BK=64: 32 MFMA per barrier pair (m97-proven shape), halves vmcnt(0) drains.
// LDS 66 KB -> 2 blocks/CU; grid 512 = exact, no tail.
// ---------------------------------------------------------------------------

__device__ __forceinline__ unsigned short f2bf(float x) {
    unsigned u = __float_as_uint(x);
    unsigned r = (u + 0x7fffu + ((u >> 16) & 1u)) >> 16;   // RNE
    return (unsigned short)r;
}
__device__ __forceinline__ float bf2f(unsigned short h) {
    return __uint_as_float(((unsigned)h) << 16);
}

// full tie-break compare (merge kernel only — arbitrary id order there)
__device__ __forceinline__ bool better(float v, int id, float v2, int id2) {
    return (v > v2) || (v == v2 && id < id2);
}
__device__ __forceinline__ void insert6(float v, int id, float* tv, int* ti) {
    if (!better(v, id, tv[TOPK - 1], ti[TOPK - 1])) return;
    int j = TOPK - 1;
    while (j > 0 && better(v, id, tv[j - 1], ti[j - 1])) {
        tv[j] = tv[j - 1]; ti[j] = ti[j - 1]; --j;
    }
    tv[j] = v; ti[j] = id;
}

// strict insert: candidate ids strictly ascending per thread stream, so
// strict '>' implements the lower-index tie-break exactly.
__device__ __forceinline__ void ins(float v, int id, float* tv, int* ti) {
    if (v <= tv[TOPK - 1]) return;
    int j = TOPK - 1;
    while (j > 0 && v > tv[j - 1]) {
        tv[j] = tv[j - 1]; ti[j] = ti[j - 1]; --j;
    }
    tv[j] = v; ti[j] = id;
}

__device__ __forceinline__ void async16(const unsigned short* g, unsigned short* l) {
    __builtin_amdgcn_global_load_lds(
        (const __attribute__((address_space(1))) void*)g,
        (__attribute__((address_space(3))) void*)l, 16, 0, 0);
}

// --- 1) normalize + split hi/lo bf16, packed [hi|lo], XOR-swizzled chunks ---
__global__ __launch_bounds__(128) void prep_kernel(
        const float* __restrict__ q, const float* __restrict__ kb,
        unsigned short* __restrict__ Q2, unsigned short* __restrict__ K2) {
    const int b = blockIdx.x;
    const bool isQ = (b < NROWS);
    const int r = isQ ? b : b - NROWS;
    const float* src = (isQ ? q : kb) + (size_t)r * DIM;
    unsigned short* D = (isQ ? Q2 : K2) + (size_t)r * DIM2;

    const int t = threadIdx.x;          // 0..127, handles elems 8t..8t+7
    float4 v0 = *(const float4*)(src + t * 8);
    float4 v1 = *(const float4*)(src + t * 8 + 4);
    float s = v0.x * v0.x + v0.y * v0.y + v0.z * v0.z + v0.w * v0.w
            + v1.x * v1.x + v1.y * v1.y + v1.z * v1.z + v1.w * v1.w;
    for (int o = 32; o; o >>= 1) s += __shfl_down(s, o, 64);
    __shared__ float wsum[2];
    __shared__ float inv_s;
    int lane = t & 63, wid = t >> 6;
    if (lane == 0) wsum[wid] = s;
    __syncthreads();
    if (t == 0)
        inv_s = 1.0f / fmaxf(sqrtf(wsum[0] + wsum[1]), 1e-12f);
    __syncthreads();
    const float inv = inv_s;

    float xs[8] = {v0.x * inv, v0.y * inv, v0.z * inv, v0.w * inv,
                   v1.x * inv, v1.y * inv, v1.z * inv, v1.w * inv};
    bf16x8 hi, lo;
#pragma unroll
    for (int i = 0; i < 8; ++i) {
        unsigned short h = f2bf(xs[i]);
        hi[i] = (short)h;
        lo[i] = (short)f2bf(xs[i] - bf2f(h));
    }
    // chunk t: k-block kb = t>>3, chunk-in-block kc = t&7, swizzled position
    const int off = (t >> 3) * 64 + (((t & 7) ^ (r & 7)) * 8);
    *(bf16x8*)(D + off)       = hi;
    *(bf16x8*)(D + DIM + off) = lo;
}

// --- 2) single K=2048 MFMA GEMM (BK=64, swizzled LDS) + fused top-6 ---------
__global__ __launch_bounds__(256) void gemm_topk_kernel(
        const unsigned short* __restrict__ Q2, const unsigned short* __restrict__ K2,
        float2* __restrict__ partials) {
    __shared__ unsigned short As[QB * 64];    // 16 KB
    __shared__ unsigned short Bs[KBT * 64];   // 16 KB
    __shared__ float Sims[128 * SST];         // 34 KB

    const int tid = threadIdx.x;
    const int w = tid >> 6, l = tid & 63;
    const int l15 = l & 15, l4 = l >> 4;
    const int qbase = blockIdx.x * QB;
    const int sbase = blockIdx.y * KPS;
    const int mbase = (w & 1) * 64, nbase = (w >> 1) * 64;

    // staging: thread covers 16B chunk (tid + j*256); row = chunk>>3
    const int arow  = tid >> 3;          // 0..31 (+ j*32)
    const int akoff = (tid & 7) * 8;     // position within k-block (swizzled)

    float tv[TOPK]; int ti[TOPK];
#pragma unroll
    for (int i = 0; i < TOPK; ++i) { tv[i] = -INFINITY; ti[i] = 0x7fffffff; }
    const int trow = tid >> 1;           // persistent top-k row 0..127
    const int tq   = tid & 1;            // 32-col quarter selector

    // fragment bases: row stride 64 elems; swizzle inverted per row (l15&7)
    const int xr = l15 & 7;
    const int fa_row = (mbase + l15) * 64;    // + mt*1024
    const int fb_row = (nbase + l15) * 64;    // + nt*1024

    const size_t abase0 = (size_t)(qbase + arow) * DIM2 + akoff;

    for (int kt = 0; kt < NKT; ++kt) {
        f32x4 acc[4][4];
#pragma unroll
        for (int mt = 0; mt < 4; ++mt)
#pragma unroll
            for (int nt = 0; nt < 4; ++nt) acc[mt][nt] = (f32x4){0.f, 0.f, 0.f, 0.f};

        const size_t bbase0 = (size_t)(sbase + kt * KBT + arow) * DIM2 + akoff;

#pragma unroll 1
        for (int k0 = 0; k0 < DIM2; k0 += 64) {
#pragma unroll
            for (int j = 0; j < 4; ++j)
                async16(Q2 + abase0 + (size_t)j * 32 * DIM2 + k0,
                        As + (tid + j * 256) * 8);
#pragma unroll
            for (int j = 0; j < 4; ++j)
                async16(K2 + bbase0 + (size_t)j * 32 * DIM2 + k0,
                        Bs + (tid + j * 256) * 8);
            __syncthreads();   // drains vmcnt (global_load_lds)
#pragma unroll
            for (int ks = 0; ks < 2; ++ks) {
                const int p8 = ((ks * 4 + l4) ^ xr) * 8;
                bf16x8 af[4], bf[4];
#pragma unroll
                for (int mt = 0; mt < 4; ++mt)
                    af[mt] = *(const bf16x8*)(As + fa_row + mt * 1024 + p8);
#pragma unroll
                for (int nt = 0; nt < 4; ++nt)
                    bf[nt] = *(const bf16x8*)(Bs + fb_row + nt * 1024 + p8);
#pragma unroll
                for (int mt = 0; mt < 4; ++mt)
#pragma unroll
                    for (int nt = 0; nt < 4; ++nt)
                        acc[mt][nt] = __builtin_amdgcn_mfma_f32_16x16x32_bf16(
                            af[mt], bf[nt], acc[mt][nt], 0, 0, 0);
            }
            __syncthreads();
        }

        // ---- fused top-k: two col-half phases, all 256 threads scan --------
        const int tile0 = sbase + kt * KBT;

        // phase A: waves 0,1 (nbase==0) hold cols 0..63 for all 128 rows
        if (nbase == 0) {
#pragma unroll
            for (int mt = 0; mt < 4; ++mt) {
                const int r0 = mbase + mt * 16 + l4 * 4;
#pragma unroll
                for (int nt = 0; nt < 4; ++nt) {
                    const int c = nt * 16 + l15;        // local col 0..63
                    Sims[(r0 + 0) * SST + c] = acc[mt][nt].x;
                    Sims[(r0 + 1) * SST + c] = acc[mt][nt].y;
                    Sims[(r0 + 2) * SST + c] = acc[mt][nt].z;
                    Sims[(r0 + 3) * SST + c] = acc[mt][nt].w;
                }
            }
        }
        __syncthreads();
        {
            const float* sp = Sims + trow * SST + tq * 32;
            const int idc0 = tile0 + tq * 32;
#pragma unroll
            for (int j = 0; j < 8; ++j) {
                float4 v = *(const float4*)(sp + 4 * j);
                float m = fmaxf(fmaxf(v.x, v.y), fmaxf(v.z, v.w));
                if (m > tv[TOPK - 1]) {
                    const int idc = idc0 + 4 * j;
                    ins(v.x, idc + 0, tv, ti);
                    ins(v.y, idc + 1, tv, ti);
                    ins(v.z, idc + 2, tv, ti);
                    ins(v.w, idc + 3, tv, ti);
                }
            }
        }
        __syncthreads();

        // phase B: waves 2,3 (nbase==64) hold cols 64..127
        if (nbase == 64) {
#pragma unroll
            for (int mt = 0; mt < 4; ++mt) {
                const int r0 = mbase + mt * 16 + l4 * 4;
#pragma unroll
                for (int nt = 0; nt < 4; ++nt) {
                    const int c = nt * 16 + l15;        // local col 0..63
                    Sims[(r0 + 0) * SST + c] = acc[mt][nt].x;
                    Sims[(r0 + 1) * SST + c] = acc[mt][nt].y;
                    Sims[(r0 + 2) * SST + c] = acc[mt][nt].z;
                    Sims[(r0 + 3) * SST + c] = acc[mt][nt].w;
                }
            }
        }
        __syncthreads();
        {
            const float* sp = Sims + trow * SST + tq * 32;
            const int idc0 = tile0 + 64 + tq * 32;
#pragma unroll
            for (int j = 0; j < 8; ++j) {
                float4 v = *(const float4*)(sp + 4 * j);
                float m = fmaxf(fmaxf(v.x, v.y), fmaxf(v.z, v.w));
                if (m > tv[TOPK - 1]) {
                    const int idc = idc0 + 4 * j;
                    ins(v.x, idc + 0, tv, ti);
                    ins(v.y, idc + 1, tv, ti);
                    ins(v.z, idc + 2, tv, ti);
                    ins(v.w, idc + 3, tv, ti);
                }
            }
        }
        // no barrier needed: next kt's staging barrier precedes Sims reuse
    }

    size_t off = (((size_t)(qbase + trow) * 2 * NSLICE) + blockIdx.y * 2 + tq) * TOPK;
#pragma unroll
    for (int i = 0; i < TOPK; ++i)
        partials[off + i] = make_float2(tv[i], __int_as_float(ti[i]));
}

// --- 3) merge 16 partial lists per row, count matches on ranks 1..5 ---------
__global__ __launch_bounds__(256) void merge_kernel(
        const float2* __restrict__ partials,
        const int* __restrict__ query_ids, const int* __restrict__ key_ids,
        int* __restrict__ counter) {
    int row = blockIdx.x * blockDim.x + threadIdx.x;
    float tv[TOPK]; int ti[TOPK];
#pragma unroll
    for (int i = 0; i < TOPK; ++i) { tv[i] = -INFINITY; ti[i] = 0x7fffffff; }
    const float2* p = partials + (size_t)row * 2 * NSLICE * TOPK;
    for (int l = 0; l < 2 * NSLICE * TOPK; ++l) {
        float2 e = p[l];
        insert6(e.x, __float_as_int(e.y), tv, ti);
    }
    int qid = query_ids[row];
    int cnt = 0;
#pragma unroll
    for (int r = 1; r < TOPK; ++r)
        cnt += (key_ids[ti[r]] == qid) ? 1 : 0;

    for (int o = 32; o; o >>= 1) cnt += __shfl_down(cnt, o, 64);
    __shared__ int sc[4];
    int lane = threadIdx.x & 63, wid = threadIdx.x >> 6;
    if (lane == 0) sc[wid] = cnt;
    __syncthreads();
    if (threadIdx.x == 0) atomicAdd(counter, sc[0] + sc[1] + sc[2] + sc[3]);
}

// --- 4) finalize ------------------------------------------------------------
__global__ void finalize_kernel(const int* __restrict__ counter,
                                float* __restrict__ out) {
    out[0] = (float)(*counter) / (float)(NROWS * KSEL);
}

extern "C" void kernel_launch(void* const* d_in, const int* in_sizes, int n_in,
                              void* d_out, int out_size, void* d_ws, size_t ws_size,
                              hipStream_t stream) {
    (void)in_sizes; (void)n_in; (void)out_size; (void)ws_size;
    const int*   query_ids = (const int*)d_in[0];
    const int*   key_ids   = (const int*)d_in[1];
    const float* q         = (const float*)d_in[2];
    const float* kb        = (const float*)d_in[3];

    char* ws = (char*)d_ws;
    const size_t MB32 = (size_t)NROWS * DIM2 * sizeof(unsigned short);  // 32 MB
    int*            counter  = (int*)ws;
    unsigned short* Q2       = (unsigned short*)(ws + 256);
    unsigned short* K2       = (unsigned short*)(ws + 256 + MB32);
    float2*         partials = (float2*)(ws + 256 + 2 * MB32);

    hipMemsetAsync(counter, 0, sizeof(int), stream);
    prep_kernel<<<2 * NROWS, 128, 0, stream>>>(q, kb, Q2, K2);
    gemm_topk_kernel<<<dim3(NROWS / QB, NSLICE), 256, 0, stream>>>(Q2, K2, partials);
    merge_kernel<<<NROWS / 256, 256, 0, stream>>>(partials, query_ids, key_ids, counter);
    finalize_kernel<<<1, 1, 0, stream>>>(counter, (float*)d_out);
}

// Round 8
// 507.230 us; speedup vs baseline: 1.6048x; 1.0541x over previous
//
#include <hip/hip_runtime.h>
#include <math.h>

#define NROWS 8192
#define DIM   1024
#define DIM2  2048           // merged hi|lo K dimension
#define KSEL  5
#define TOPK  6
#define QB    128            // query rows per block
#define KBT   128            // key cols per tile
#define NSLICE 8
#define KPS   (NROWS / NSLICE)   // keys per slice = 1024
#define NKT   (KPS / KBT)        // key tiles per slice = 8

typedef __attribute__((ext_vector_type(8))) short bf16x8;
typedef __attribute__((ext_vector_type(4))) float f32x4;

// ---------------------------------------------------------------------------
// ws layout:
//   [0]          : int match counter
//   [256]        : Q2 bf16[8192][2048]  (hi | lo, XOR-swizzled)   32 MB
//   [+32M]       : K2 bf16[8192][2048]  (hi | lo, XOR-swizzled)   32 MB
//   [+64M]       : partials float2[8192][16][TOPK]  (~6.3 MB)
//
// Round-8 restructure: TRANSPOSED MFMA (A=keys, B=queries -> C[key][query]).
// Each thread's acc holds 16 keys x 4 query-cols, so top-6 selection runs
// directly on registers (4 lists/thread, max16-gated) — the Sims LDS
// round-trip, its 4 barriers/kt, and 34 KB of LDS are gone. Partial lists
// (8 per query-col per block) are block-merged through the staging LDS
// (free after the K-loop) down to 2 lists/query/block = same partials
// layout as round 7. XOR global swizzle keeps LDS reads conflict-free
// (round-7 evidence: SQ_LDS_BANK_CONFLICT = 0). BK=64, grid 512 = 2/CU.
// ---------------------------------------------------------------------------

__device__ __forceinline__ unsigned short f2bf(float x) {
    unsigned u = __float_as_uint(x);
    unsigned r = (u + 0x7fffu + ((u >> 16) & 1u)) >> 16;   // RNE
    return (unsigned short)r;
}
__device__ __forceinline__ float bf2f(unsigned short h) {
    return __uint_as_float(((unsigned)h) << 16);
}

// full tie-break compare (merge paths — arbitrary id order there)
__device__ __forceinline__ bool better(float v, int id, float v2, int id2) {
    return (v > v2) || (v == v2 && id < id2);
}
__device__ __forceinline__ void insert6(float v, int id, float* tv, int* ti) {
    if (!better(v, id, tv[TOPK - 1], ti[TOPK - 1])) return;
    int j = TOPK - 1;
    while (j > 0 && better(v, id, tv[j - 1], ti[j - 1])) {
        tv[j] = tv[j - 1]; ti[j] = ti[j - 1]; --j;
    }
    tv[j] = v; ti[j] = id;
}

// branchless strict insert (ascending-id stream => strict '>' is exact).
// All indices compile-time so tv/ti stay in registers.
__device__ __forceinline__ void ins6(float v, int id, float* tv, int* ti) {
    if (v <= tv[5]) return;
    bool gt[6];
#pragma unroll
    for (int j = 0; j < 6; ++j) gt[j] = v > tv[j];
#pragma unroll
    for (int j = 5; j >= 1; --j)
        if (gt[j - 1]) { tv[j] = tv[j - 1]; ti[j] = ti[j - 1]; }
    if (gt[0]) { tv[0] = v; ti[0] = id; }
#pragma unroll
    for (int j = 1; j < 6; ++j)
        if (gt[j] && !gt[j - 1]) { tv[j] = v; ti[j] = id; }
}

__device__ __forceinline__ void async16(const unsigned short* g, unsigned short* l) {
    __builtin_amdgcn_global_load_lds(
        (const __attribute__((address_space(1))) void*)g,
        (__attribute__((address_space(3))) void*)l, 16, 0, 0);
}

// --- 1) normalize + split hi/lo bf16, packed [hi|lo], XOR-swizzled chunks ---
__global__ __launch_bounds__(128) void prep_kernel(
        const float* __restrict__ q, const float* __restrict__ kb,
        unsigned short* __restrict__ Q2, unsigned short* __restrict__ K2) {
    const int b = blockIdx.x;
    const bool isQ = (b < NROWS);
    const int r = isQ ? b : b - NROWS;
    const float* src = (isQ ? q : kb) + (size_t)r * DIM;
    unsigned short* D = (isQ ? Q2 : K2) + (size_t)r * DIM2;

    const int t = threadIdx.x;          // 0..127, handles elems 8t..8t+7
    float4 v0 = *(const float4*)(src + t * 8);
    float4 v1 = *(const float4*)(src + t * 8 + 4);
    float s = v0.x * v0.x + v0.y * v0.y + v0.z * v0.z + v0.w * v0.w
            + v1.x * v1.x + v1.y * v1.y + v1.z * v1.z + v1.w * v1.w;
    for (int o = 32; o; o >>= 1) s += __shfl_down(s, o, 64);
    __shared__ float wsum[2];
    __shared__ float inv_s;
    int lane = t & 63, wid = t >> 6;
    if (lane == 0) wsum[wid] = s;
    __syncthreads();
    if (t == 0)
        inv_s = 1.0f / fmaxf(sqrtf(wsum[0] + wsum[1]), 1e-12f);
    __syncthreads();
    const float inv = inv_s;

    float xs[8] = {v0.x * inv, v0.y * inv, v0.z * inv, v0.w * inv,
                   v1.x * inv, v1.y * inv, v1.z * inv, v1.w * inv};
    bf16x8 hi, lo;
#pragma unroll
    for (int i = 0; i < 8; ++i) {
        unsigned short h = f2bf(xs[i]);
        hi[i] = (short)h;
        lo[i] = (short)f2bf(xs[i] - bf2f(h));
    }
    // chunk t: k-block t>>3, chunk-in-block t&7, swizzled by row&7
    const int off = (t >> 3) * 64 + (((t & 7) ^ (r & 7)) * 8);
    *(bf16x8*)(D + off)       = hi;
    *(bf16x8*)(D + DIM + off) = lo;
}

// --- 2) transposed K=2048 MFMA GEMM + in-register per-col top-6 -------------
__global__ __launch_bounds__(256) void gemm_topk_kernel(
        const unsigned short* __restrict__ Q2, const unsigned short* __restrict__ K2,
        float2* __restrict__ partials) {
    // smem: K-loop = Ks[128*64] + Qs[128*64] bf16 (32 KB);
    //       merge  = float2[128 q][8 slots][6]  (48 KB)
    __shared__ __align__(16) char smem[49152];
    unsigned short* Ks = (unsigned short*)smem;          // A-operand (keys)
    unsigned short* Qs = Ks + QB * 64;                   // B-operand (queries)
    float2* mbuf = (float2*)smem;

    const int tid = threadIdx.x;
    const int w = tid >> 6, l = tid & 63;
    const int l15 = l & 15, l4 = l >> 4;
    const int qbase = blockIdx.x * QB;
    const int sbase = blockIdx.y * KPS;
    const int mbase = (w & 1) * 64;      // key-rows half
    const int nbase = (w >> 1) * 64;     // query-cols half

    // staging: thread covers 16B chunk (tid + j*256); row = chunk>>3
    const int arow  = tid >> 3;          // 0..31 (+ j*32)
    const int akoff = (tid & 7) * 8;     // swizzled position within k-block

    // 4 per-thread top-6 lists, one per query col (nt)
    float tvl[4][6]; int til[4][6];
#pragma unroll
    for (int n = 0; n < 4; ++n)
#pragma unroll
        for (int i = 0; i < 6; ++i) { tvl[n][i] = -INFINITY; til[n][i] = 0x7fffffff; }

    // fragment bases: row stride 64 elems; swizzle inverted per row (l15&7)
    const int xr = l15 & 7;
    const int fa_row = (mbase + l15) * 64;    // keys,    + mt*1024
    const int fb_row = (nbase + l15) * 64;    // queries, + nt*1024

    const size_t qstage = (size_t)(qbase + arow) * DIM2 + akoff;   // kt-invariant

    for (int kt = 0; kt < NKT; ++kt) {
        f32x4 acc[4][4];   // [mt = key-tile][nt = query-tile]
#pragma unroll
        for (int mt = 0; mt < 4; ++mt)
#pragma unroll
            for (int nt = 0; nt < 4; ++nt) acc[mt][nt] = (f32x4){0.f, 0.f, 0.f, 0.f};

        const size_t kstage = (size_t)(sbase + kt * KBT + arow) * DIM2 + akoff;

#pragma unroll 1
        for (int k0 = 0; k0 < DIM2; k0 += 64) {
#pragma unroll
            for (int j = 0; j < 4; ++j)
                async16(K2 + kstage + (size_t)j * 32 * DIM2 + k0,
                        Ks + (tid + j * 256) * 8);
#pragma unroll
            for (int j = 0; j < 4; ++j)
                async16(Q2 + qstage + (size_t)j * 32 * DIM2 + k0,
                        Qs + (tid + j * 256) * 8);
            __syncthreads();   // drains vmcnt (global_load_lds)
#pragma unroll
            for (int ks = 0; ks < 2; ++ks) {
                const int p8 = ((ks * 4 + l4) ^ xr) * 8;
                bf16x8 af[4], bf[4];
#pragma unroll
                for (int mt = 0; mt < 4; ++mt)
                    af[mt] = *(const bf16x8*)(Ks + fa_row + mt * 1024 + p8);
#pragma unroll
                for (int nt = 0; nt < 4; ++nt)
                    bf[nt] = *(const bf16x8*)(Qs + fb_row + nt * 1024 + p8);
#pragma unroll
                for (int mt = 0; mt < 4; ++mt)
#pragma unroll
                    for (int nt = 0; nt < 4; ++nt)
                        acc[mt][nt] = __builtin_amdgcn_mfma_f32_16x16x32_bf16(
                            af[mt], bf[nt], acc[mt][nt], 0, 0, 0);
            }
            __syncthreads();
        }

        // ---- in-register top-6 update: keys = C-rows live in this thread ---
        const int kb0 = sbase + kt * KBT + mbase + l4 * 4;
#pragma unroll
        for (int nt = 0; nt < 4; ++nt) {
            float m = acc[0][nt].x;
#pragma unroll
            for (int mt = 0; mt < 4; ++mt) {
                m = fmaxf(m, fmaxf(fmaxf(acc[mt][nt].x, acc[mt][nt].y),
                                   fmaxf(acc[mt][nt].z, acc[mt][nt].w)));
            }
            if (m > tvl[nt][5]) {
#pragma unroll
                for (int mt = 0; mt < 4; ++mt) {
                    const int kk = kb0 + mt * 16;
                    ins6(acc[mt][nt].x, kk + 0, tvl[nt], til[nt]);
                    ins6(acc[mt][nt].y, kk + 1, tvl[nt], til[nt]);
                    ins6(acc[mt][nt].z, kk + 2, tvl[nt], til[nt]);
                    ins6(acc[mt][nt].w, kk + 3, tvl[nt], til[nt]);
                }
            }
        }
        // no barrier needed: next kt's staging barrier precedes LDS reuse
    }

    // ---- block merge: 8 slots per query col -> 2 lists per query ----------
    __syncthreads();                     // all K-loop LDS reads long done
    const int slot = (w & 1) * 4 + l4;   // 0..7
#pragma unroll
    for (int nt = 0; nt < 4; ++nt) {
        const int ql = nbase + nt * 16 + l15;        // local query 0..127
        float2* dst = mbuf + ((size_t)ql * 8 + slot) * 6;
#pragma unroll
        for (int e = 0; e < 6; ++e)
            dst[e] = make_float2(tvl[nt][e], __int_as_float(til[nt][e]));
    }
    __syncthreads();

    {
        const int qloc = tid >> 1;       // 0..127
        const int half = tid & 1;        // slots 0-3 or 4-7
        float tv[6]; int ti[6];
#pragma unroll
        for (int i = 0; i < 6; ++i) { tv[i] = -INFINITY; ti[i] = 0x7fffffff; }
        const float2* src = mbuf + ((size_t)qloc * 8 + half * 4) * 6;
        for (int e = 0; e < 24; ++e) {
            float2 p = src[e];
            if (p.x < tv[5]) continue;
            insert6(p.x, __float_as_int(p.y), tv, ti);
        }
        size_t off = (((size_t)(qbase + qloc) * 2 * NSLICE) + blockIdx.y * 2 + half) * TOPK;
#pragma unroll
        for (int i = 0; i < 6; ++i)
            partials[off + i] = make_float2(tv[i], __int_as_float(ti[i]));
    }
}

// --- 3) merge 16 partial lists per row, count matches on ranks 1..5 ---------
__global__ __launch_bounds__(256) void merge_kernel(
        const float2* __restrict__ partials,
        const int* __restrict__ query_ids, const int* __restrict__ key_ids,
        int* __restrict__ counter) {
    int row = blockIdx.x * blockDim.x + threadIdx.x;
    float tv[TOPK]; int ti[TOPK];
#pragma unroll
    for (int i = 0; i < TOPK; ++i) { tv[i] = -INFINITY; ti[i] = 0x7fffffff; }
    const float2* p = partials + (size_t)row * 2 * NSLICE * TOPK;
    for (int l = 0; l < 2 * NSLICE * TOPK; ++l) {
        float2 e = p[l];
        if (e.x < tv[TOPK - 1]) continue;
        insert6(e.x, __float_as_int(e.y), tv, ti);
    }
    int qid = query_ids[row];
    int cnt = 0;
#pragma unroll
    for (int r = 1; r < TOPK; ++r)
        cnt += (key_ids[ti[r]] == qid) ? 1 : 0;

    for (int o = 32; o; o >>= 1) cnt += __shfl_down(cnt, o, 64);
    __shared__ int sc[4];
    int lane = threadIdx.x & 63, wid = threadIdx.x >> 6;
    if (lane == 0) sc[wid] = cnt;
    __syncthreads();
    if (threadIdx.x == 0) atomicAdd(counter, sc[0] + sc[1] + sc[2] + sc[3]);
}

// --- 4) finalize ------------------------------------------------------------
__global__ void finalize_kernel(const int* __restrict__ counter,
                                float* __restrict__ out) {
    out[0] = (float)(*counter) / (float)(NROWS * KSEL);
}

extern "C" void kernel_launch(void* const* d_in, const int* in_sizes, int n_in,
                              void* d_out, int out_size, void* d_ws, size_t ws_size,
                              hipStream_t stream) {
    (void)in_sizes; (void)n_in; (void)out_size; (void)ws_size;
    const int*   query_ids = (const int*)d_in[0];
    const int*   key_ids   = (const int*)d_in[1];
    const float* q         = (const float*)d_in[2];
    const float* kb        = (const float*)d_in[3];

    char* ws = (char*)d_ws;
    const size_t MB32 = (size_t)NROWS * DIM2 * sizeof(unsigned short);  // 32 MB
    int*            counter  = (int*)ws;
    unsigned short* Q2       = (unsigned short*)(ws + 256);
    unsigned short* K2       = (unsigned short*)(ws + 256 + MB32);
    float2*         partials = (float2*)(ws + 256 + 2 * MB32);

    hipMemsetAsync(counter, 0, sizeof(int), stream);
    prep_kernel<<<2 * NROWS, 128, 0, stream>>>(q, kb, Q2, K2);
    gemm_topk_kernel<<<dim3(NROWS / QB, NSLICE), 256, 0, stream>>>(Q2, K2, partials);
    merge_kernel<<<NROWS / 256, 256, 0, stream>>>(partials, query_ids, key_ids, counter);
    finalize_kernel<<<1, 1, 0, stream>>>(counter, (float*)d_out);
}

// Round 9
// 501.687 us; speedup vs baseline: 1.6225x; 1.0110x over previous
//
#include <hip/hip_runtime.h>
#include <math.h>

#define NROWS 8192
#define DIM   1024
#define DIM2  2048           // merged hi|lo K dimension
#define KSEL  5
#define TOPK  6
#define QB    128            // queries per block
#define KBB   256            // keys per block
#define NKB   (NROWS / KBB)  // key blocks = 32

typedef __attribute__((ext_vector_type(8))) short bf16x8;
typedef __attribute__((ext_vector_type(4))) float f32x4;

// ---------------------------------------------------------------------------
// ws layout:
//   [0]          : int match counter
//   [256]        : Q2 bf16[8192][2048]  (hi | lo, XOR-swizzled)   32 MB
//   [+32M]       : K2 bf16[8192][2048]  (hi | lo, XOR-swizzled)   32 MB
//   [+64M]       : partials float2[8192][32][TOPK]  (12.6 MB)
//
// Round-9: 256-key x 128-query block (acc[8][4] = 128 AGPR, wave = 128 keys
// x 64 queries). 12 ds_read_b128 feed 32 MFMA (was 8:16), 64 MFMA per
// barrier-pair (was 32), single accumulator lifetime per block -> top-6
// scan runs ONCE per block, Q-tile staged once. XOR global swizzle keeps
// LDS reads conflict-free (round-7: SQ_LDS_BANK_CONFLICT 3.36e7 -> 0).
// __launch_bounds__(256,2): 2 waves/SIMD needs <=256 unified regs/wave.
// ---------------------------------------------------------------------------

__device__ __forceinline__ unsigned short f2bf(float x) {
    unsigned u = __float_as_uint(x);
    unsigned r = (u + 0x7fffu + ((u >> 16) & 1u)) >> 16;   // RNE
    return (unsigned short)r;
}
__device__ __forceinline__ float bf2f(unsigned short h) {
    return __uint_as_float(((unsigned)h) << 16);
}

// full tie-break compare (merge paths — arbitrary id order there)
__device__ __forceinline__ bool better(float v, int id, float v2, int id2) {
    return (v > v2) || (v == v2 && id < id2);
}
__device__ __forceinline__ void insert6(float v, int id, float* tv, int* ti) {
    if (!better(v, id, tv[TOPK - 1], ti[TOPK - 1])) return;
    int j = TOPK - 1;
    while (j > 0 && better(v, id, tv[j - 1], ti[j - 1])) {
        tv[j] = tv[j - 1]; ti[j] = ti[j - 1]; --j;
    }
    tv[j] = v; ti[j] = id;
}

// branchless strict insert (ascending-id stream => strict '>' is exact).
__device__ __forceinline__ void ins6(float v, int id, float* tv, int* ti) {
    if (v <= tv[5]) return;
    bool gt[6];
#pragma unroll
    for (int j = 0; j < 6; ++j) gt[j] = v > tv[j];
#pragma unroll
    for (int j = 5; j >= 1; --j)
        if (gt[j - 1]) { tv[j] = tv[j - 1]; ti[j] = ti[j - 1]; }
    if (gt[0]) { tv[0] = v; ti[0] = id; }
#pragma unroll
    for (int j = 1; j < 6; ++j)
        if (gt[j] && !gt[j - 1]) { tv[j] = v; ti[j] = id; }
}

__device__ __forceinline__ void async16(const unsigned short* g, unsigned short* l) {
    __builtin_amdgcn_global_load_lds(
        (const __attribute__((address_space(1))) void*)g,
        (__attribute__((address_space(3))) void*)l, 16, 0, 0);
}

// --- 1) normalize + split hi/lo bf16, packed [hi|lo], XOR-swizzled chunks ---
__global__ __launch_bounds__(128) void prep_kernel(
        const float* __restrict__ q, const float* __restrict__ kb,
        unsigned short* __restrict__ Q2, unsigned short* __restrict__ K2) {
    const int b = blockIdx.x;
    const bool isQ = (b < NROWS);
    const int r = isQ ? b : b - NROWS;
    const float* src = (isQ ? q : kb) + (size_t)r * DIM;
    unsigned short* D = (isQ ? Q2 : K2) + (size_t)r * DIM2;

    const int t = threadIdx.x;          // 0..127, handles elems 8t..8t+7
    float4 v0 = *(const float4*)(src + t * 8);
    float4 v1 = *(const float4*)(src + t * 8 + 4);
    float s = v0.x * v0.x + v0.y * v0.y + v0.z * v0.z + v0.w * v0.w
            + v1.x * v1.x + v1.y * v1.y + v1.z * v1.z + v1.w * v1.w;
    for (int o = 32; o; o >>= 1) s += __shfl_down(s, o, 64);
    __shared__ float wsum[2];
    __shared__ float inv_s;
    int lane = t & 63, wid = t >> 6;
    if (lane == 0) wsum[wid] = s;
    __syncthreads();
    if (t == 0)
        inv_s = 1.0f / fmaxf(sqrtf(wsum[0] + wsum[1]), 1e-12f);
    __syncthreads();
    const float inv = inv_s;

    float xs[8] = {v0.x * inv, v0.y * inv, v0.z * inv, v0.w * inv,
                   v1.x * inv, v1.y * inv, v1.z * inv, v1.w * inv};
    bf16x8 hi, lo;
#pragma unroll
    for (int i = 0; i < 8; ++i) {
        unsigned short h = f2bf(xs[i]);
        hi[i] = (short)h;
        lo[i] = (short)f2bf(xs[i] - bf2f(h));
    }
    // chunk t: k-block t>>3, chunk-in-block t&7, swizzled by row&7
    const int off = (t >> 3) * 64 + (((t & 7) ^ (r & 7)) * 8);
    *(bf16x8*)(D + off)       = hi;
    *(bf16x8*)(D + DIM + off) = lo;
}

// --- 2) 256x128 transposed MFMA GEMM + in-register top-6 --------------------
__global__ __launch_bounds__(256, 2) void gemm_topk_kernel(
        const unsigned short* __restrict__ Q2, const unsigned short* __restrict__ K2,
        float2* __restrict__ partials) {
    // K-loop: Ks[256*64] (32 KB) + Qs[128*64] (16 KB); merge: 48 KB (alias)
    __shared__ __align__(16) char smem[49152];
    unsigned short* Ks = (unsigned short*)smem;          // A-operand (keys)
    unsigned short* Qs = Ks + KBB * 64;                  // B-operand (queries)
    float2* mbuf = (float2*)smem;                        // [128 q][8 slot][6]

    const int tid = threadIdx.x;
    const int w = tid >> 6, l = tid & 63;
    const int l15 = l & 15, l4 = l >> 4;
    const int qbase = blockIdx.x * QB;
    const int kbase = blockIdx.y * KBB;
    const int wkh = w & 1;               // key half   (128 keys)
    const int wqh = w >> 1;              // query half (64 queries)

    const int arow  = tid >> 3;          // 0..31 (+ j*32)
    const int akoff = (tid & 7) * 8;     // swizzled position within k-block

    const int xr = l15 & 7;
    const int fa_row = (wkh * 128 + l15) * 64;   // + mt*1024
    const int fb_row = (wqh * 64 + l15) * 64;    // + nt*1024

    const size_t qstage = (size_t)(qbase + arow) * DIM2 + akoff;
    const size_t kstage = (size_t)(kbase + arow) * DIM2 + akoff;

    f32x4 acc[8][4];   // [mt = key-tile][nt = query-tile]
#pragma unroll
    for (int mt = 0; mt < 8; ++mt)
#pragma unroll
        for (int nt = 0; nt < 4; ++nt) acc[mt][nt] = (f32x4){0.f, 0.f, 0.f, 0.f};

#pragma unroll 1
    for (int k0 = 0; k0 < DIM2; k0 += 64) {
#pragma unroll
        for (int j = 0; j < 8; ++j)
            async16(K2 + kstage + (size_t)j * 32 * DIM2 + k0,
                    Ks + (tid + j * 256) * 8);
#pragma unroll
        for (int j = 0; j < 4; ++j)
            async16(Q2 + qstage + (size_t)j * 32 * DIM2 + k0,
                    Qs + (tid + j * 256) * 8);
        __syncthreads();   // drains vmcnt (global_load_lds)
#pragma unroll
        for (int ks = 0; ks < 2; ++ks) {
            const int p8 = ((ks * 4 + l4) ^ xr) * 8;
            bf16x8 af[8], bf[4];
#pragma unroll
            for (int mt = 0; mt < 8; ++mt)
                af[mt] = *(const bf16x8*)(Ks + fa_row + mt * 1024 + p8);
#pragma unroll
            for (int nt = 0; nt < 4; ++nt)
                bf[nt] = *(const bf16x8*)(Qs + fb_row + nt * 1024 + p8);
#pragma unroll
            for (int mt = 0; mt < 8; ++mt)
#pragma unroll
                for (int nt = 0; nt < 4; ++nt)
                    acc[mt][nt] = __builtin_amdgcn_mfma_f32_16x16x32_bf16(
                        af[mt], bf[nt], acc[mt][nt], 0, 0, 0);
        }
        __syncthreads();
    }

    // ---- in-register top-6 (once per block): 32 keys/thread per nt-list ----
    float tvl[4][6]; int til[4][6];
#pragma unroll
    for (int n = 0; n < 4; ++n)
#pragma unroll
        for (int i = 0; i < 6; ++i) { tvl[n][i] = -INFINITY; til[n][i] = 0x7fffffff; }

#pragma unroll
    for (int nt = 0; nt < 4; ++nt) {
#pragma unroll
        for (int mt = 0; mt < 8; ++mt) {
            const f32x4 a = acc[mt][nt];
            const float m4 = fmaxf(fmaxf(a.x, a.y), fmaxf(a.z, a.w));
            if (m4 > tvl[nt][5]) {
                const int kk = kbase + wkh * 128 + mt * 16 + l4 * 4;
                ins6(a.x, kk + 0, tvl[nt], til[nt]);
                ins6(a.y, kk + 1, tvl[nt], til[nt]);
                ins6(a.z, kk + 2, tvl[nt], til[nt]);
                ins6(a.w, kk + 3, tvl[nt], til[nt]);
            }
        }
    }

    // ---- block merge: 8 slots per query -> 1 list per query ---------------
    __syncthreads();                     // all K-loop LDS reads done
    const int slot = wkh * 4 + l4;       // 0..7
#pragma unroll
    for (int nt = 0; nt < 4; ++nt) {
        const int ql = wqh * 64 + nt * 16 + l15;     // local query 0..127
        float2* dst = mbuf + ((size_t)ql * 8 + slot) * 6;
#pragma unroll
        for (int e = 0; e < 6; ++e)
            dst[e] = make_float2(tvl[nt][e], __int_as_float(til[nt][e]));
    }
    __syncthreads();

    if (tid < 128) {                     // one thread per query merges 8 lists
        float tv[6]; int ti[6];
#pragma unroll
        for (int i = 0; i < 6; ++i) { tv[i] = -INFINITY; ti[i] = 0x7fffffff; }
        const float2* src = mbuf + (size_t)tid * 48;
        for (int e = 0; e < 48; ++e) {
            float2 p = src[e];
            if (p.x < tv[5]) continue;
            insert6(p.x, __float_as_int(p.y), tv, ti);
        }
        size_t off = ((size_t)(qbase + tid) * NKB + blockIdx.y) * TOPK;
#pragma unroll
        for (int i = 0; i < 6; ++i)
            partials[off + i] = make_float2(tv[i], __int_as_float(ti[i]));
    }
}

// --- 3) merge 32 partial lists per row, count matches on ranks 1..5 ---------
__global__ __launch_bounds__(256) void merge_kernel(
        const float2* __restrict__ partials,
        const int* __restrict__ query_ids, const int* __restrict__ key_ids,
        int* __restrict__ counter) {
    int row = blockIdx.x * blockDim.x + threadIdx.x;
    float tv[TOPK]; int ti[TOPK];
#pragma unroll
    for (int i = 0; i < TOPK; ++i) { tv[i] = -INFINITY; ti[i] = 0x7fffffff; }
    const float2* p = partials + (size_t)row * NKB * TOPK;
    for (int l = 0; l < NKB * TOPK; ++l) {
        float2 e = p[l];
        if (e.x < tv[TOPK - 1]) continue;
        insert6(e.x, __float_as_int(e.y), tv, ti);
    }
    int qid = query_ids[row];
    int cnt = 0;
#pragma unroll
    for (int r = 1; r < TOPK; ++r)
        cnt += (key_ids[ti[r]] == qid) ? 1 : 0;

    for (int o = 32; o; o >>= 1) cnt += __shfl_down(cnt, o, 64);
    __shared__ int sc[4];
    int lane = threadIdx.x & 63, wid = threadIdx.x >> 6;
    if (lane == 0) sc[wid] = cnt;
    __syncthreads();
    if (threadIdx.x == 0) atomicAdd(counter, sc[0] + sc[1] + sc[2] + sc[3]);
}

// --- 4) finalize ------------------------------------------------------------
__global__ void finalize_kernel(const int* __restrict__ counter,
                                float* __restrict__ out) {
    out[0] = (float)(*counter) / (float)(NROWS * KSEL);
}

extern "C" void kernel_launch(void* const* d_in, const int* in_sizes, int n_in,
                              void* d_out, int out_size, void* d_ws, size_t ws_size,
                              hipStream_t stream) {
    (void)in_sizes; (void)n_in; (void)out_size; (void)ws_size;
    const int*   query_ids = (const int*)d_in[0];
    const int*   key_ids   = (const int*)d_in[1];
    const float* q         = (const float*)d_in[2];
    const float* kb        = (const float*)d_in[3];

    char* ws = (char*)d_ws;
    const size_t MB32 = (size_t)NROWS * DIM2 * sizeof(unsigned short);  // 32 MB
    int*            counter  = (int*)ws;
    unsigned short* Q2       = (unsigned short*)(ws + 256);
    unsigned short* K2       = (unsigned short*)(ws + 256 + MB32);
    float2*         partials = (float2*)(ws + 256 + 2 * MB32);

    hipMemsetAsync(counter, 0, sizeof(int), stream);
    prep_kernel<<<2 * NROWS, 128, 0, stream>>>(q, kb, Q2, K2);
    gemm_topk_kernel<<<dim3(NROWS / QB, NKB), 256, 0, stream>>>(Q2, K2, partials);
    merge_kernel<<<NROWS / 256, 256, 0, stream>>>(partials, query_ids, key_ids, counter);
    finalize_kernel<<<1, 1, 0, stream>>>(counter, (float*)d_out);
}